// Round 1
// 459.108 us; speedup vs baseline: 1.0630x; 1.0630x over previous
//
#include <hip/hip_runtime.h>

typedef int int4v __attribute__((ext_vector_type(4)));

#define BM 256
#define BN 256
#define BKB 128  // int8 elements (bytes) along K per K-tile = 2 MFMA K-steps

// Async global->LDS, 16B per lane; HW writes wave-uniform base + lane*16.
__device__ __forceinline__ void async_copy16(const void* g, void* l) {
  __builtin_amdgcn_global_load_lds((const __attribute__((address_space(1))) void*)g,
                                   (__attribute__((address_space(3))) void*)l, 16, 0, 0);
}

// One dispatch: blocks [0,xb) reduce x (n4x float4s), rest reduce w.
__global__ __launch_bounds__(256) void absmax2_kernel(
    const float* __restrict__ x, size_t n4x,
    const float* __restrict__ w, size_t n4w,
    unsigned* __restrict__ out, int xb) {
  const float4* src;
  size_t n4;
  unsigned* dst;
  int bid, nb;
  if ((int)blockIdx.x < xb) {
    src = (const float4*)x; n4 = n4x; dst = out; bid = blockIdx.x; nb = xb;
  } else {
    src = (const float4*)w; n4 = n4w; dst = out + 1; bid = blockIdx.x - xb; nb = gridDim.x - xb;
  }
  size_t i = (size_t)bid * blockDim.x + threadIdx.x;
  size_t stride = (size_t)nb * blockDim.x;
  float m = 0.0f;
  for (; i < n4; i += stride) {
    float4 v = src[i];
    m = fmaxf(m, fmaxf(fmaxf(fabsf(v.x), fabsf(v.y)), fmaxf(fabsf(v.z), fabsf(v.w))));
  }
#pragma unroll
  for (int off = 32; off > 0; off >>= 1)
    m = fmaxf(m, __shfl_down(m, off, 64));
  __shared__ float red[4];
  int wave = threadIdx.x >> 6, lane = threadIdx.x & 63;
  if (lane == 0) red[wave] = m;
  __syncthreads();
  if (threadIdx.x == 0) {
    m = fmaxf(fmaxf(red[0], red[1]), fmaxf(red[2], red[3]));
    atomicMax(dst, __float_as_uint(m));  // non-negative: uint order == float order
  }
}

// One dispatch: quantize x -> qx (int8, [-128,127]) and w -> qw ([-127,127]).
__global__ __launch_bounds__(256) void quant2_kernel(
    const float* __restrict__ x, char* __restrict__ qx, size_t nx,
    const float* __restrict__ w, char* __restrict__ qw, size_t nw,
    const unsigned* __restrict__ amax, int xb) {
  const float* src;
  char* dst;
  size_t n;
  float r, lo;
  int bid, nb;
  if ((int)blockIdx.x < xb) {
    src = x; dst = qx; n = nx; r = 127.0f / __uint_as_float(amax[0]);
    lo = -128.0f; bid = blockIdx.x; nb = xb;
  } else {
    src = w; dst = qw; n = nw; r = 127.0f / __uint_as_float(amax[1]);
    lo = -127.0f; bid = blockIdx.x - xb; nb = gridDim.x - xb;
  }
  size_t i = ((size_t)bid * blockDim.x + threadIdx.x) * 8;
  size_t stride = (size_t)nb * blockDim.x * 8;
  for (; i < n; i += stride) {
    float4 v0 = *(const float4*)(src + i);
    float4 v1 = *(const float4*)(src + i + 4);
    float f[8] = {v0.x, v0.y, v0.z, v0.w, v1.x, v1.y, v1.z, v1.w};
    unsigned w0 = 0, w1 = 0;
#pragma unroll
    for (int j = 0; j < 4; ++j) {
      int q0 = (int)fminf(fmaxf(rintf(f[j] * r), lo), 127.0f);
      int q1 = (int)fminf(fmaxf(rintf(f[4 + j] * r), lo), 127.0f);
      w0 |= (unsigned)(q0 & 0xff) << (8 * j);
      w1 |= (unsigned)(q1 & 0xff) << (8 * j);
    }
    uint2 u; u.x = w0; u.y = w1;
    *(uint2*)(dst + i) = u;
  }
}

// ---------------------------------------------------------------------------
// 256x256 8-phase int8 GEMM (T1+T2+T3+T4+T5), isomorphic to the m201 bf16
// template: BKB=128 B/row (same bytes as bf16 BK=64), 8 waves 2Mx4N,
// 2-deep LDS dbuf (128 KiB), XOR slot swizzle, counted vmcnt(4)/K-tile,
// setprio around each 16-MFMA quadrant cluster.
// Per phase: one C-quadrant (mh,nh); ALL waves read the same A-half/B-half,
// so one counted vmcnt per K-tile is sufficient and 2-deep buffering is
// race-free (each half is overwritten only after the closing barrier of the
// last phase that reads it).
// ---------------------------------------------------------------------------

// stage one 128-row half (16 KB) of A or B: 2 x global_load_lds per wave.
#define STAGE_A(buf_, t_, rowb_) do {                                          \
    int r0_ = (rowb_) + wave * 8;                                              \
    async_copy16(gA + (size_t)r0_ * K + (size_t)(t_) * BKB,                    \
                 &As[buf_][r0_ * BKB]);                                        \
    async_copy16(gA + (size_t)(r0_ + 64) * K + (size_t)(t_) * BKB,             \
                 &As[buf_][(r0_ + 64) * BKB]);                                 \
  } while (0)

#define STAGE_B(buf_, t_, rowb_) do {                                          \
    int r0_ = (rowb_) + wave * 8;                                              \
    async_copy16(gB + (size_t)r0_ * K + (size_t)(t_) * BKB,                    \
                 &Bs[buf_][r0_ * BKB]);                                        \
    async_copy16(gB + (size_t)(r0_ + 64) * K + (size_t)(t_) * BKB,             \
                 &Bs[buf_][(r0_ + 64) * BKB]);                                 \
  } while (0)

#define VM4 asm volatile("s_waitcnt vmcnt(4)" ::: "memory")
#define VM0 asm volatile("s_waitcnt vmcnt(0)" ::: "memory")
#define VMN ((void)0)
#define NOSTG ((void)0)

#define MFMA_I8 __builtin_amdgcn_mfma_i32_16x16x64_i8

// One phase: 12 ds_read_b128, stage 1 half (2 loads), barrier, 16 MFMA.
#define PHASE(bb_, mh_, nh_, STG, VMW) do {                                    \
    asm volatile("" ::: "memory");                                             \
    const char* Ab_ = &As[bb_][((mh_)*128 + wr * 64 + r16) * BKB];             \
    const char* Bb_ = &Bs[bb_][((nh_)*128 + wc * 32 + r16) * BKB];             \
    int4v a00_ = *(const int4v*)(Ab_ + 0 * 16 * BKB + slot0);                  \
    int4v a01_ = *(const int4v*)(Ab_ + 0 * 16 * BKB + slot1);                  \
    int4v a10_ = *(const int4v*)(Ab_ + 1 * 16 * BKB + slot0);                  \
    int4v a11_ = *(const int4v*)(Ab_ + 1 * 16 * BKB + slot1);                  \
    int4v a20_ = *(const int4v*)(Ab_ + 2 * 16 * BKB + slot0);                  \
    int4v a21_ = *(const int4v*)(Ab_ + 2 * 16 * BKB + slot1);                  \
    int4v a30_ = *(const int4v*)(Ab_ + 3 * 16 * BKB + slot0);                  \
    int4v a31_ = *(const int4v*)(Ab_ + 3 * 16 * BKB + slot1);                  \
    int4v b00_ = *(const int4v*)(Bb_ + 0 * 16 * BKB + slot0);                  \
    int4v b01_ = *(const int4v*)(Bb_ + 0 * 16 * BKB + slot1);                  \
    int4v b10_ = *(const int4v*)(Bb_ + 1 * 16 * BKB + slot0);                  \
    int4v b11_ = *(const int4v*)(Bb_ + 1 * 16 * BKB + slot1);                  \
    STG;                                                                       \
    __builtin_amdgcn_s_barrier();                                              \
    __builtin_amdgcn_s_setprio(1);                                             \
    acc[mh_][nh_][0][0] = MFMA_I8(a00_, b00_, acc[mh_][nh_][0][0], 0, 0, 0);   \
    acc[mh_][nh_][0][0] = MFMA_I8(a01_, b01_, acc[mh_][nh_][0][0], 0, 0, 0);   \
    acc[mh_][nh_][0][1] = MFMA_I8(a00_, b10_, acc[mh_][nh_][0][1], 0, 0, 0);   \
    acc[mh_][nh_][0][1] = MFMA_I8(a01_, b11_, acc[mh_][nh_][0][1], 0, 0, 0);   \
    acc[mh_][nh_][1][0] = MFMA_I8(a10_, b00_, acc[mh_][nh_][1][0], 0, 0, 0);   \
    acc[mh_][nh_][1][0] = MFMA_I8(a11_, b01_, acc[mh_][nh_][1][0], 0, 0, 0);   \
    acc[mh_][nh_][1][1] = MFMA_I8(a10_, b10_, acc[mh_][nh_][1][1], 0, 0, 0);   \
    acc[mh_][nh_][1][1] = MFMA_I8(a11_, b11_, acc[mh_][nh_][1][1], 0, 0, 0);   \
    acc[mh_][nh_][2][0] = MFMA_I8(a20_, b00_, acc[mh_][nh_][2][0], 0, 0, 0);   \
    acc[mh_][nh_][2][0] = MFMA_I8(a21_, b01_, acc[mh_][nh_][2][0], 0, 0, 0);   \
    acc[mh_][nh_][2][1] = MFMA_I8(a20_, b10_, acc[mh_][nh_][2][1], 0, 0, 0);   \
    acc[mh_][nh_][2][1] = MFMA_I8(a21_, b11_, acc[mh_][nh_][2][1], 0, 0, 0);   \
    acc[mh_][nh_][3][0] = MFMA_I8(a30_, b00_, acc[mh_][nh_][3][0], 0, 0, 0);   \
    acc[mh_][nh_][3][0] = MFMA_I8(a31_, b01_, acc[mh_][nh_][3][0], 0, 0, 0);   \
    acc[mh_][nh_][3][1] = MFMA_I8(a30_, b10_, acc[mh_][nh_][3][1], 0, 0, 0);   \
    acc[mh_][nh_][3][1] = MFMA_I8(a31_, b11_, acc[mh_][nh_][3][1], 0, 0, 0);   \
    __builtin_amdgcn_s_setprio(0);                                             \
    VMW;                                                                       \
    asm volatile("" ::: "memory");                                             \
    __builtin_amdgcn_s_barrier();                                              \
  } while (0)

__global__ __launch_bounds__(512, 2) void gemm_i8_kernel(
    const char* __restrict__ qx, const char* __restrict__ qw,
    const float* __restrict__ bias, const unsigned* __restrict__ amax,
    float* __restrict__ out, int M, int N, int K) {
  __shared__ __align__(16) char As[2][BM * BKB];  // 64 KB
  __shared__ __align__(16) char Bs[2][BN * BKB];  // 64 KB
  const int tid = threadIdx.x;
  const int wave = tid >> 6, lane = tid & 63;
  const int wr = wave >> 2, wc = wave & 3;  // 2 (M) x 4 (N) waves

  // T1: XCD-aware swizzle (grid 512 % 8 == 0): each XCD gets a contiguous
  // tile chunk, bm fastest -> B panel (1 MB) stays hot in that XCD's L2.
  int tilesM = M / BM, tilesN = N / BN;
  int T = tilesM * tilesN;
  int p = blockIdx.x;
  int tile;
  if ((T & 7) == 0) tile = (p & 7) * (T >> 3) + (p >> 3);
  else tile = p;
  int bm = (tile % tilesM) * BM;
  int bn = (tile / tilesM) * BN;

  // T2 staging (rule #21): LDS dest linear, global source pre-swizzled.
  // LDS (row, slot s) holds global (row, s ^ (row&7)); 16B slots, 8/row.
  const int grow = lane >> 3;                    // row within 8-row group
  const int gcol = ((lane & 7) ^ grow) * 16;     // pre-swizzled source col
  const char* gA = qx + (size_t)(bm + grow) * K + gcol;
  const char* gB = qw + (size_t)(bn + grow) * K + gcol;

  // T2 read side: fragment row = ...+ (lane&15) => row&7 == lane&7 always.
  const int r16 = lane & 15, hi = lane >> 4;
  const int slot0 = ((0 + hi) ^ (lane & 7)) * 16;  // k-step 0
  const int slot1 = ((4 + hi) ^ (lane & 7)) * 16;  // k-step 1

  const int NT = K >> 7;  // K-tiles of 128

  int4v acc[2][2][4][2] = {};  // [mh][nh][m][n] — all indices compile-time

  // Prologue: tile0 fully + tile1 A-lo,B-lo; wait oldest 8 (tile0), keep 4.
  STAGE_A(0, 0, 0);
  STAGE_B(0, 0, 0);
  STAGE_A(0, 0, 128);
  STAGE_B(0, 0, 128);
  STAGE_A(1, 1, 0);
  STAGE_B(1, 1, 0);
  VM4;
  __builtin_amdgcn_s_barrier();

  // Steady state (2 K-tiles per iteration, 8 phases). Staging plan per tile t:
  //   ph0: t+1 A-hi (other buf)   ph1: t+1 B-hi (other buf)
  //   ph2: t+2 A-lo (this buf — A-lo last read at ph1)
  //   ph3: t+2 B-lo (this buf — B-lo last read at ph2), then vmcnt(4)
  // vmcnt(4) leaves exactly {t+2 A-lo, t+2 B-lo} in flight; everything the
  // next tile reads has landed before the closing barrier.
  int t = 0;
  for (; t + 3 < NT; t += 2) {
    PHASE(0, 0, 0, STAGE_A(1, t + 1, 128), VMN);
    PHASE(0, 0, 1, STAGE_B(1, t + 1, 128), VMN);
    PHASE(0, 1, 0, STAGE_A(0, t + 2, 0), VMN);
    PHASE(0, 1, 1, STAGE_B(0, t + 2, 0), VM4);
    PHASE(1, 0, 0, STAGE_A(0, t + 2, 128), VMN);
    PHASE(1, 0, 1, STAGE_B(0, t + 2, 128), VMN);
    PHASE(1, 1, 0, STAGE_A(1, t + 3, 0), VMN);
    PHASE(1, 1, 1, STAGE_B(1, t + 3, 0), VM4);
  }
  // Tail: t = NT-2 (buf 0): stage only NT-1's hi halves, then drain.
  PHASE(0, 0, 0, STAGE_A(1, NT - 1, 128), VMN);
  PHASE(0, 0, 1, STAGE_B(1, NT - 1, 128), VMN);
  PHASE(0, 1, 0, NOSTG, VMN);
  PHASE(0, 1, 1, NOSTG, VM0);
  // t = NT-1 (buf 1): pure compute.
  PHASE(1, 0, 0, NOSTG, VMN);
  PHASE(1, 0, 1, NOSTG, VMN);
  PHASE(1, 1, 0, NOSTG, VMN);
  PHASE(1, 1, 1, NOSTG, VMN);

  // Epilogue. C/D layout (16x16, dtype-independent): col=lane&15,
  // row=(lane>>4)*4+reg.
  float fx = __uint_as_float(amax[0]) * (1.0f / 127.0f);
  float fw = __uint_as_float(amax[1]) * (1.0f / 127.0f);
  float scale = 4.0f * fx * fw;
  int col16 = lane & 15;
  int rq = (lane >> 4) << 2;
#pragma unroll
  for (int mh = 0; mh < 2; ++mh)
#pragma unroll
    for (int nh = 0; nh < 2; ++nh)
#pragma unroll
      for (int n = 0; n < 2; ++n) {
        int gn = bn + nh * 128 + wc * 32 + n * 16 + col16;
        float b4 = 4.0f * bias[gn];
#pragma unroll
        for (int m = 0; m < 4; ++m) {
          size_t base = (size_t)(bm + mh * 128 + wr * 64 + m * 16 + rq) * N + gn;
#pragma unroll
          for (int rr = 0; rr < 4; ++rr)
            __builtin_nontemporal_store(
                scale * (float)acc[mh][nh][m][n][rr] + b4,
                out + base + (size_t)rr * N);
        }
      }
}

extern "C" void kernel_launch(void* const* d_in, const int* in_sizes, int n_in,
                              void* d_out, int out_size, void* d_ws, size_t ws_size,
                              hipStream_t stream) {
  const float* x = (const float*)d_in[0];
  const float* W = (const float*)d_in[1];
  const float* b = (const float*)d_in[2];
  float* out = (float*)d_out;

  int Nv = in_sizes[2];          // OUT = 4096
  int K = in_sizes[1] / Nv;      // IN  = 4096
  int M = in_sizes[0] / K;       // N rows = 8192

  size_t nx = (size_t)M * K, nw = (size_t)Nv * K;
  unsigned* amax = (unsigned*)d_ws;        // [0]=max|x| bits, [1]=max|W| bits
  char* qx = (char*)d_ws + 256;            // M*K int8
  char* qw = qx + nx;                      // Nv*K int8

  hipMemsetAsync(d_ws, 0, 8, stream);
  absmax2_kernel<<<1536, 256, 0, stream>>>(x, nx / 4, W, nw / 4, amax, 1024);
  quant2_kernel<<<3072, 256, 0, stream>>>(x, qx, nx, W, qw, nw, amax, 2048);
  gemm_i8_kernel<<<(M / BM) * (Nv / BN), 512, 0, stream>>>(qx, qw, b, amax, out, M, Nv, K);
}

// Round 2
// 442.843 us; speedup vs baseline: 1.1020x; 1.0367x over previous
//
#include <hip/hip_runtime.h>

typedef int int4v __attribute__((ext_vector_type(4)));
typedef int int16v __attribute__((ext_vector_type(16)));

#define BM 256
#define BN 256
#define BKB 128  // int8 bytes along K per K-tile = 4 MFMA K-steps of 32

// Async global->LDS, 16B per lane; HW writes wave-uniform base + lane*16.
__device__ __forceinline__ void async_copy16(const void* g, void* l) {
  __builtin_amdgcn_global_load_lds((const __attribute__((address_space(1))) void*)g,
                                   (__attribute__((address_space(3))) void*)l, 16, 0, 0);
}

// One dispatch: blocks [0,xb) reduce x (n4x float4s), rest reduce w.
__global__ __launch_bounds__(256) void absmax2_kernel(
    const float* __restrict__ x, size_t n4x,
    const float* __restrict__ w, size_t n4w,
    unsigned* __restrict__ out, int xb) {
  const float4* src;
  size_t n4;
  unsigned* dst;
  int bid, nb;
  if ((int)blockIdx.x < xb) {
    src = (const float4*)x; n4 = n4x; dst = out; bid = blockIdx.x; nb = xb;
  } else {
    src = (const float4*)w; n4 = n4w; dst = out + 1; bid = blockIdx.x - xb; nb = gridDim.x - xb;
  }
  size_t i = (size_t)bid * blockDim.x + threadIdx.x;
  size_t stride = (size_t)nb * blockDim.x;
  float m = 0.0f;
  for (; i < n4; i += stride) {
    float4 v = src[i];
    m = fmaxf(m, fmaxf(fmaxf(fabsf(v.x), fabsf(v.y)), fmaxf(fabsf(v.z), fabsf(v.w))));
  }
#pragma unroll
  for (int off = 32; off > 0; off >>= 1)
    m = fmaxf(m, __shfl_down(m, off, 64));
  __shared__ float red[4];
  int wave = threadIdx.x >> 6, lane = threadIdx.x & 63;
  if (lane == 0) red[wave] = m;
  __syncthreads();
  if (threadIdx.x == 0) {
    m = fmaxf(fmaxf(red[0], red[1]), fmaxf(red[2], red[3]));
    atomicMax(dst, __float_as_uint(m));  // non-negative: uint order == float order
  }
}

// One dispatch: quantize x -> qx (int8, [-128,127]) and w -> qw ([-127,127]).
__global__ __launch_bounds__(256) void quant2_kernel(
    const float* __restrict__ x, char* __restrict__ qx, size_t nx,
    const float* __restrict__ w, char* __restrict__ qw, size_t nw,
    const unsigned* __restrict__ amax, int xb) {
  const float* src;
  char* dst;
  size_t n;
  float r, lo;
  int bid, nb;
  if ((int)blockIdx.x < xb) {
    src = x; dst = qx; n = nx; r = 127.0f / __uint_as_float(amax[0]);
    lo = -128.0f; bid = blockIdx.x; nb = xb;
  } else {
    src = w; dst = qw; n = nw; r = 127.0f / __uint_as_float(amax[1]);
    lo = -127.0f; bid = blockIdx.x - xb; nb = gridDim.x - xb;
  }
  size_t i = ((size_t)bid * blockDim.x + threadIdx.x) * 8;
  size_t stride = (size_t)nb * blockDim.x * 8;
  for (; i < n; i += stride) {
    float4 v0 = *(const float4*)(src + i);
    float4 v1 = *(const float4*)(src + i + 4);
    float f[8] = {v0.x, v0.y, v0.z, v0.w, v1.x, v1.y, v1.z, v1.w};
    unsigned w0 = 0, w1 = 0;
#pragma unroll
    for (int j = 0; j < 4; ++j) {
      int q0 = (int)fminf(fmaxf(rintf(f[j] * r), lo), 127.0f);
      int q1 = (int)fminf(fmaxf(rintf(f[4 + j] * r), lo), 127.0f);
      w0 |= (unsigned)(q0 & 0xff) << (8 * j);
      w1 |= (unsigned)(q1 & 0xff) << (8 * j);
    }
    uint2 u; u.x = w0; u.y = w1;
    *(uint2*)(dst + i) = u;
  }
}

// ---------------------------------------------------------------------------
// 256x256 int8 GEMM on mfma_i32_32x32x32_i8.
// Why 32x32: one ds_read_b128 per MFMA operand now feeds a 65536-op MFMA, so
// LDS traffic per K-tile is 24 reads/wave (2313 cyc @85 B/cyc) vs MFMA work
// 2614 cyc -> compute-bound (the 16x16x64 version needed 48 reads -> LDS-bound).
// Schedule: whole-tile 2-deep dbuf; stage tile t+1 (8 global_load_lds/wave) at
// the START of tile t, vmcnt(0)+barrier at tile END (~2600 cyc in-flight slack
// >> 900 cyc HBM latency, so the drain is cheap). 1 barrier per K-tile.
// T2 swizzle unchanged: LDS (row, slot) holds global (row, slot^(row&7)),
// staged via pre-swizzled global source (linear LDS dest, rule #21).
// ---------------------------------------------------------------------------

// Stage a full K-tile of A and B (32 KB each) into buf_: 8 loads per wave.
#define STAGE_ALL(buf_, t_) do {                                               \
    const char* ga_ = gA + (size_t)(t_) * BKB;                                 \
    const char* gb_ = gB + (size_t)(t_) * BKB;                                 \
    int r0_ = wave * 8;                                                        \
    async_copy16(ga_ + (size_t)(r0_      ) * K, &As[buf_][(r0_      ) * BKB]); \
    async_copy16(ga_ + (size_t)(r0_ +  64) * K, &As[buf_][(r0_ +  64) * BKB]); \
    async_copy16(ga_ + (size_t)(r0_ + 128) * K, &As[buf_][(r0_ + 128) * BKB]); \
    async_copy16(ga_ + (size_t)(r0_ + 192) * K, &As[buf_][(r0_ + 192) * BKB]); \
    async_copy16(gb_ + (size_t)(r0_      ) * K, &Bs[buf_][(r0_      ) * BKB]); \
    async_copy16(gb_ + (size_t)(r0_ +  64) * K, &Bs[buf_][(r0_ +  64) * BKB]); \
    async_copy16(gb_ + (size_t)(r0_ + 128) * K, &Bs[buf_][(r0_ + 128) * BKB]); \
    async_copy16(gb_ + (size_t)(r0_ + 192) * K, &Bs[buf_][(r0_ + 192) * BKB]); \
  } while (0)

#define VM0 asm volatile("s_waitcnt vmcnt(0)" ::: "memory")
#define BAR do { asm volatile("" ::: "memory");                                \
                 __builtin_amdgcn_s_barrier();                                 \
                 asm volatile("" ::: "memory"); } while (0)

#define MFMA32 __builtin_amdgcn_mfma_i32_32x32x32_i8

// One K-step (K=32): 6 ds_read_b128 (4 A-frags, 2 B-frags) + 8 MFMA.
#define KSTEP(so_) do {                                                        \
    int4v a0_ = *(const int4v*)(Ab_ + 0 * 32 * BKB + (so_));                   \
    int4v a1_ = *(const int4v*)(Ab_ + 1 * 32 * BKB + (so_));                   \
    int4v a2_ = *(const int4v*)(Ab_ + 2 * 32 * BKB + (so_));                   \
    int4v a3_ = *(const int4v*)(Ab_ + 3 * 32 * BKB + (so_));                   \
    int4v b0_ = *(const int4v*)(Bb_ + 0 * 32 * BKB + (so_));                   \
    int4v b1_ = *(const int4v*)(Bb_ + 1 * 32 * BKB + (so_));                   \
    __builtin_amdgcn_s_setprio(1);                                             \
    acc[0][0] = MFMA32(a0_, b0_, acc[0][0], 0, 0, 0);                          \
    acc[0][1] = MFMA32(a0_, b1_, acc[0][1], 0, 0, 0);                          \
    acc[1][0] = MFMA32(a1_, b0_, acc[1][0], 0, 0, 0);                          \
    acc[1][1] = MFMA32(a1_, b1_, acc[1][1], 0, 0, 0);                          \
    acc[2][0] = MFMA32(a2_, b0_, acc[2][0], 0, 0, 0);                          \
    acc[2][1] = MFMA32(a2_, b1_, acc[2][1], 0, 0, 0);                          \
    acc[3][0] = MFMA32(a3_, b0_, acc[3][0], 0, 0, 0);                          \
    acc[3][1] = MFMA32(a3_, b1_, acc[3][1], 0, 0, 0);                          \
    __builtin_amdgcn_s_setprio(0);                                             \
  } while (0)

// Full K-tile: 4 K-steps over buf bb_.
#define COMPUTE(bb_) do {                                                      \
    const char* Ab_ = &As[bb_][(wr * 128 + r32) * BKB];                        \
    const char* Bb_ = &Bs[bb_][(wc * 64 + r32) * BKB];                         \
    KSTEP(so0); KSTEP(so1); KSTEP(so2); KSTEP(so3);                            \
  } while (0)

__global__ __launch_bounds__(512, 2) void gemm_i8_kernel(
    const char* __restrict__ qx, const char* __restrict__ qw,
    const float* __restrict__ bias, const unsigned* __restrict__ amax,
    float* __restrict__ out, int M, int N, int K) {
  __shared__ __align__(16) char As[2][BM * BKB];  // 64 KB
  __shared__ __align__(16) char Bs[2][BN * BKB];  // 64 KB
  const int tid = threadIdx.x;
  const int wave = tid >> 6, lane = tid & 63;
  const int wr = wave >> 2, wc = wave & 3;  // 2 (M) x 4 (N) waves

  // T1: XCD-aware swizzle (grid 512 % 8 == 0): each XCD gets a contiguous
  // tile chunk, bm fastest -> B panel (1 MB) stays hot in that XCD's L2.
  int tilesM = M / BM, tilesN = N / BN;
  int T = tilesM * tilesN;
  int p = blockIdx.x;
  int tile;
  if ((T & 7) == 0) tile = (p & 7) * (T >> 3) + (p >> 3);
  else tile = p;
  int bm = (tile % tilesM) * BM;
  int bn = (tile / tilesM) * BN;

  // T2 staging (rule #21): LDS dest linear, global source pre-swizzled.
  // LDS (row, slot s) holds global (row, s ^ (row&7)); 16B slots, 8/row.
  const int grow = lane >> 3;                    // row within 8-row group
  const int gcol = ((lane & 7) ^ grow) * 16;     // pre-swizzled source col
  const char* gA = qx + (size_t)(bm + grow) * K + gcol;
  const char* gB = qw + (size_t)(bn + grow) * K + gcol;

  // Read side: fragment row = base + (lane&31), bases are multiples of 32,
  // so row&7 == lane&7. K-chunk for kstep ks = ks*2 + (lane>>5).
  const int r32 = lane & 31, hi = lane >> 5, l7 = lane & 7;
  const int so0 = ((0 + hi) ^ l7) * 16;
  const int so1 = ((2 + hi) ^ l7) * 16;
  const int so2 = ((4 + hi) ^ l7) * 16;
  const int so3 = ((6 + hi) ^ l7) * 16;

  const int NT = K >> 7;  // K-tiles of 128 (even: K=4096 -> 32)

  int16v acc[4][2] = {};  // [m][n] 32x32 tiles; 128 VGPRs

  // Prologue: tile 0 into buf 0.
  STAGE_ALL(0, 0);
  VM0;
  BAR;

  // Steady state: stage t+1 at tile start (loads fly during the whole tile's
  // compute), drain+barrier at tile end. Writes go to the buffer whose last
  // readers finished before the previous barrier -> race-free.
  int t = 0;
  for (; t < NT - 2; t += 2) {
    STAGE_ALL(1, t + 1);
    COMPUTE(0);
    VM0; BAR;
    STAGE_ALL(0, t + 2);
    COMPUTE(1);
    VM0; BAR;
  }
  // t == NT-2:
  STAGE_ALL(1, NT - 1);
  COMPUTE(0);
  VM0; BAR;
  COMPUTE(1);

  // Epilogue. C/D layout for 32x32 (m74/m101, dtype-independent):
  // col = lane&31 (n-dim), row = (reg&3) + 8*(reg>>2) + 4*(lane>>5) (m-dim).
  float fx = __uint_as_float(amax[0]) * (1.0f / 127.0f);
  float fw = __uint_as_float(amax[1]) * (1.0f / 127.0f);
  float scale = 4.0f * fx * fw;
  int col = lane & 31;
  int rbh = 4 * hi;
#pragma unroll
  for (int n = 0; n < 2; ++n) {
    int gn = bn + wc * 64 + n * 32 + col;
    float b4 = 4.0f * bias[gn];
#pragma unroll
    for (int m = 0; m < 4; ++m) {
      size_t rowb = (size_t)(bm + wr * 128 + m * 32 + rbh);
#pragma unroll
      for (int g = 0; g < 4; ++g)
#pragma unroll
        for (int rr = 0; rr < 4; ++rr)
          __builtin_nontemporal_store(
              scale * (float)acc[m][n][g * 4 + rr] + b4,
              out + (rowb + g * 8 + rr) * N + gn);
    }
  }
}

extern "C" void kernel_launch(void* const* d_in, const int* in_sizes, int n_in,
                              void* d_out, int out_size, void* d_ws, size_t ws_size,
                              hipStream_t stream) {
  const float* x = (const float*)d_in[0];
  const float* W = (const float*)d_in[1];
  const float* b = (const float*)d_in[2];
  float* out = (float*)d_out;

  int Nv = in_sizes[2];          // OUT = 4096
  int K = in_sizes[1] / Nv;      // IN  = 4096
  int M = in_sizes[0] / K;       // N rows = 8192

  size_t nx = (size_t)M * K, nw = (size_t)Nv * K;
  unsigned* amax = (unsigned*)d_ws;        // [0]=max|x| bits, [1]=max|W| bits
  char* qx = (char*)d_ws + 256;            // M*K int8
  char* qw = qx + nx;                      // Nv*K int8

  hipMemsetAsync(d_ws, 0, 8, stream);
  absmax2_kernel<<<1536, 256, 0, stream>>>(x, nx / 4, W, nw / 4, amax, 1024);
  quant2_kernel<<<3072, 256, 0, stream>>>(x, qx, nx, W, qw, nw, amax, 2048);
  gemm_i8_kernel<<<(M / BM) * (Nv / BN), 512, 0, stream>>>(qx, qw, b, amax, out, M, Nv, K);
}